// Round 10
// baseline (96.710 us; speedup 1.0000x reference)
//
#include <hip/hip_runtime.h>
#include <math.h>

typedef unsigned int uint32;
typedef _Float16 f16x8 __attribute__((ext_vector_type(8)));   // 8 f16 (4 VGPRs)
typedef _Float16 f16x2 __attribute__((ext_vector_type(2)));
typedef float f32x4 __attribute__((ext_vector_type(4)));      // MFMA accumulator

union frag_u { f16x8 h; uint32 u[4]; uint4 q; };

// ---------------------------------------------------------------------------
// SparseMHA, all-f16 intermediate, TWO launches:
//   proj: per-block LDS transpose of W -> MFMA f16 (wave owns 32 rows);
//         trailing blocks compute row_ptr. Epilogue writes HEAD-MAJOR layout.
//   edge: 2 nodes per wave (half-wave each), lane=(slot 0..3, head 0..7);
//         per edge one 64B contiguous gather (4 x dwordx4), fdot2 dots,
//         2-level butterfly reduce, double-buffered.
// reshape(n,16,8) => flat idx = d*8+h, head = idx%8.
// Head-major pack: u32 at [node*64 + h*8 + i] = (f16(x[h+8i]), f16(x[h+8i+64]))
//   i.e. head h's dims d=i (lo) and d=i+8 (hi). KV entries are uint2 (k,v).
// Q pre-scaled by 16^-0.5*log2(e) => p=exp2(q.k).
// ---------------------------------------------------------------------------

__device__ __forceinline__ uint32 pack_f16(float lo, float hi) {
    auto r = __builtin_amdgcn_cvt_pkrtz(lo, hi);   // one v_cvt_pkrtz_f16_f32
    return __builtin_bit_cast(uint32, r);
}
__device__ __forceinline__ float dot2acc(uint32 a, uint32 b, float c) {
#if __has_builtin(__builtin_amdgcn_fdot2)
    return __builtin_amdgcn_fdot2(__builtin_bit_cast(f16x2, a),
                                  __builtin_bit_cast(f16x2, b), c, false);
#else
    f16x2 av = __builtin_bit_cast(f16x2, a), bv = __builtin_bit_cast(f16x2, b);
    return fmaf((float)av[0], (float)bv[0], fmaf((float)av[1], (float)bv[1], c));
#endif
}

// ---- proj (blocks < PB): in-block W transpose + MFMA; else row_ptr --------
__global__ __launch_bounds__(256) void proj_mfma_kernel(
    const float* __restrict__ h,
    const float* __restrict__ Wq, const float* __restrict__ Wk,
    const float* __restrict__ Wv,
    const float* __restrict__ bq, const float* __restrict__ bk,
    const float* __restrict__ bv,
    uint32* __restrict__ Qp, uint2* __restrict__ KV,
    const int* __restrict__ row, int* __restrict__ rp,
    int N, int E, int PB)
{
    const int t = threadIdx.x;
    if ((int)blockIdx.x >= PB) {             // ---- row_ptr tail blocks ----
        int i = ((int)blockIdx.x - PB) * 256 + t;
        if (i > N) return;
        int lo = 0, hi = E;
        while (lo < hi) {
            int mid = (lo + hi) >> 1;
            if (row[mid] < i) lo = mid + 1; else hi = mid;
        }
        rp[i] = lo;
        return;
    }

    // LDS: one matrix of Wt, u32 kpairs [n][slot^swz][rem], 32 KB
    __shared__ uint32 Wl[8192];

    const int lane = t & 63;
    const int w = t >> 6;
    const int r = lane & 15, g = lane >> 4;
    const int rbase = blockIdx.x * 128 + w * 32;   // this wave's 32 rows

    // A fragments (f16), loaded exactly once per wave
    frag_u afr[2][4];                    // [ng][kb]
    const float4* h4 = reinterpret_cast<const float4*>(h);
    #pragma unroll
    for (int ng = 0; ng < 2; ++ng) {
        int arow = rbase + ng * 16 + r;
        bool av = arow < N;
        #pragma unroll
        for (int kb = 0; kb < 4; ++kb) {
            float4 x = make_float4(0.f,0.f,0.f,0.f), y = x;
            if (av) {
                size_t base = (size_t)arow * 32 + (kb * 4 + g) * 2;
                x = h4[base]; y = h4[base + 1];
            }
            afr[ng][kb].u[0] = pack_f16(x.x, x.y);
            afr[ng][kb].u[1] = pack_f16(x.z, x.w);
            afr[ng][kb].u[2] = pack_f16(y.x, y.y);
            afr[ng][kb].u[3] = pack_f16(y.z, y.w);
        }
    }

    const float SCALE_Q = 0.25f * 1.44269504f;   // 16^-0.5 * log2(e)
    uint32 kpk[4][2][4];                         // K results held for V pass

    #pragma unroll
    for (int mat = 0; mat < 3; ++mat) {
        const float* W = (mat == 0) ? Wq : (mat == 1) ? Wk : Wv;
        const float* bias = (mat == 0) ? bq : (mat == 1) ? bk : bv;

        // ---- transpose W (f32 [k][n]) -> Wl (f16 kpairs [n][kp], swizzled)
        __syncthreads();                         // previous mat's reads done
        {
            const float4* W4 = reinterpret_cast<const float4*>(W);
            #pragma unroll
            for (int i0 = 0; i0 < 8; ++i0) {
                int i = t + i0 * 256;            // i = k2*32 + nq
                int k2 = i >> 5, nq = i & 31;
                float4 a = W4[(k2 * 2) * 32 + nq];
                float4 b = W4[(k2 * 2 + 1) * 32 + nq];
                int slot = k2 >> 2, rem = k2 & 3;
                #pragma unroll
                for (int e = 0; e < 4; ++e) {
                    int n = nq * 4 + e;
                    float lo = (e == 0) ? a.x : (e == 1) ? a.y : (e == 2) ? a.z : a.w;
                    float hi = (e == 0) ? b.x : (e == 1) ? b.y : (e == 2) ? b.z : b.w;
                    Wl[n * 64 + ((slot ^ (n & 7)) << 2) + rem] = pack_f16(lo, hi);
                }
            }
        }
        __syncthreads();

        #pragma unroll
        for (int tp = 0; tp < 4; ++tp) {         // col-tile pair {tp, tp+4}
            const int c = tp * 16 + r;           // pair col (c, c+64)
            const int pc = ((c & 7) << 3) | (c >> 3);   // head-major index

            frag_u bfr[2][4];                    // [tti][kb]
            #pragma unroll
            for (int tti = 0; tti < 2; ++tti)
                #pragma unroll
                for (int kb = 0; kb < 4; ++kb) {
                    int n = (tp + 4 * tti) * 16 + r;
                    int s = kb * 4 + g;
                    bfr[tti][kb].q = *reinterpret_cast<const uint4*>(
                        &Wl[n * 64 + ((s ^ (n & 7)) << 2)]);
                }

            f32x4 acc[2][2];
            #pragma unroll
            for (int ng = 0; ng < 2; ++ng)
                #pragma unroll
                for (int tti = 0; tti < 2; ++tti)
                    acc[ng][tti] = (f32x4){0.f, 0.f, 0.f, 0.f};

            #pragma unroll
            for (int ng = 0; ng < 2; ++ng)
                #pragma unroll
                for (int tti = 0; tti < 2; ++tti)
                    #pragma unroll
                    for (int kb = 0; kb < 4; ++kb)
                        acc[ng][tti] = __builtin_amdgcn_mfma_f32_16x16x32_f16(
                            afr[ng][kb].h, bfr[tti][kb].h, acc[ng][tti], 0, 0, 0);

            // C/D map: col=lane&15, row=g*4+reg
            float blo = bias[c], bhi = bias[c + 64];
            #pragma unroll
            for (int ng = 0; ng < 2; ++ng) {
                #pragma unroll
                for (int reg = 0; reg < 4; ++reg) {
                    int node = rbase + ng * 16 + g * 4 + reg;
                    float lo = acc[ng][0][reg] + blo;
                    float hi = acc[ng][1][reg] + bhi;
                    if (mat == 0) {
                        if (node < N)
                            Qp[(size_t)node * 64 + pc] = pack_f16(lo * SCALE_Q, hi * SCALE_Q);
                    } else if (mat == 1) {
                        kpk[tp][ng][reg] = pack_f16(lo, hi);
                    } else {
                        if (node < N)
                            KV[(size_t)node * 64 + pc] =
                                make_uint2(kpk[tp][ng][reg], pack_f16(lo, hi));
                    }
                }
            }
        }
    }
}

// ---- fused edge stage: 2 nodes/wave, lane=(slot 0..3, head) ---------------
__global__ __launch_bounds__(128) void edge_attn_kernel(
    const uint4* __restrict__ Qp4, const uint4* __restrict__ KV4,
    const int* __restrict__ rp, const int* __restrict__ col,
    float* __restrict__ out, int N)
{
    const int lane = threadIdx.x & 63;
    const int wid  = blockIdx.x * 2 + (threadIdx.x >> 6);
    const int half = lane >> 5;
    const int node = wid * 2 + half;
    const int hh   = lane & 7;             // head
    const int slot = (lane >> 3) & 3;      // edge slot within group of 4
    const bool valid = node < N;

    const int start = valid ? rp[node] : 0;
    const int end   = valid ? rp[node + 1] : 0;
    const int deg = end - start;

    int cnt = (deg + 3) >> 2;
    { int o = __shfl_xor(cnt, 32); cnt = cnt > o ? cnt : o; }   // wave-max
    if (cnt == 0) {                        // both nodes empty
        if (valid) {
            float* outp = out + (size_t)node * 128;
            int b = lane & 31;
            outp[b] = 0.f; outp[b + 32] = 0.f; outp[b + 64] = 0.f; outp[b + 96] = 0.f;
        }
        return;
    }
    const int lastc = (deg > 0) ? end - 1 : 0;

    // Q for (node, head): 8 packed pairs = 32B contiguous
    uint32 q[8];
    {
        const uint4* qrow = Qp4 + ((size_t)(valid ? node : 0) * 16 + hh * 2);
        uint4 qa = qrow[0], qb = qrow[1];
        q[0]=qa.x; q[1]=qa.y; q[2]=qa.z; q[3]=qa.w;
        q[4]=qb.x; q[5]=qb.y; q[6]=qb.z; q[7]=qb.w;
    }

    float z = 0.f;
    float acc[16];
    #pragma unroll
    for (int i = 0; i < 16; ++i) acc[i] = 0.f;

    uint4 bufA[4], bufB[4];
    // KV row for (col, head): 8 uint2 = 64B contiguous -> 4 x dwordx4
    #define LOADG(buf, c0) { \
        const uint4* kvr = KV4 + ((size_t)(c0) * 32 + hh * 4); \
        buf[0] = kvr[0]; buf[1] = kvr[1]; buf[2] = kvr[2]; buf[3] = kvr[3]; }
    // uint4 = (k_{2j}, v_{2j}, k_{2j+1}, v_{2j+1})
    #define PROC(buf, e) { \
        float s = 0.f; \
        s = dot2acc(q[0], buf[0].x, s); s = dot2acc(q[1], buf[0].z, s); \
        s = dot2acc(q[2], buf[1].x, s); s = dot2acc(q[3], buf[1].z, s); \
        s = dot2acc(q[4], buf[2].x, s); s = dot2acc(q[5], buf[2].z, s); \
        s = dot2acc(q[6], buf[3].x, s); s = dot2acc(q[7], buf[3].z, s); \
        float p = ((e) < end) ? __builtin_amdgcn_exp2f(s) : 0.f; \
        z += p; \
        _Pragma("unroll") \
        for (int j = 0; j < 4; ++j) { \
            f16x2 v0 = __builtin_bit_cast(f16x2, buf[j].y); \
            f16x2 v1 = __builtin_bit_cast(f16x2, buf[j].w); \
            acc[2*j]     = fmaf(p, (float)v0[0], acc[2*j]); \
            acc[2*j+8]   = fmaf(p, (float)v0[1], acc[2*j+8]); \
            acc[2*j+1]   = fmaf(p, (float)v1[0], acc[2*j+1]); \
            acc[2*j+9]   = fmaf(p, (float)v1[1], acc[2*j+9]); } }

    const int e0 = start + slot;
    int cA = col[min(e0, lastc)];
    LOADG(bufA, cA);
    int cB = col[min(e0 + 4, lastc)];
    int it = 0;
    while (true) {
        LOADG(bufB, cB);
        cA = col[min(e0 + (it + 2) * 4, lastc)];
        PROC(bufA, e0 + it * 4);
        ++it; if (it >= cnt) break;
        LOADG(bufA, cA);
        cB = col[min(e0 + (it + 2) * 4, lastc)];
        PROC(bufB, e0 + it * 4);
        ++it; if (it >= cnt) break;
    }

    // butterfly over the 4 slots (lane bits 3..4); halves are distinct nodes
    #pragma unroll
    for (int m = 8; m <= 16; m <<= 1) {
        z += __shfl_xor(z, m);
        #pragma unroll
        for (int i = 0; i < 16; ++i) acc[i] += __shfl_xor(acc[i], m);
    }

    const float rz = (z > 0.f) ? 1.0f / z : 0.f;
    if (valid) {
        // out flat idx = d*8 + h; lane writes d = slot, slot+4, slot+8, slot+12
        float* outp = out + (size_t)node * 128;
        int b = lane & 31;                 // = slot*8 + hh
        outp[b]      = acc[slot]      * rz;
        outp[b + 32] = acc[slot + 4]  * rz;
        outp[b + 64] = acc[slot + 8]  * rz;
        outp[b + 96] = acc[slot + 12] * rz;
    }
}

extern "C" void kernel_launch(void* const* d_in, const int* in_sizes, int n_in,
                              void* d_out, int out_size, void* d_ws, size_t ws_size,
                              hipStream_t stream)
{
    const float* h  = (const float*)d_in[0];
    const float* Wq = (const float*)d_in[1];
    const float* bq = (const float*)d_in[2];
    const float* Wk = (const float*)d_in[3];
    const float* bk = (const float*)d_in[4];
    const float* Wv = (const float*)d_in[5];
    const float* bv = (const float*)d_in[6];
    const int* row  = (const int*)d_in[7];
    const int* col  = (const int*)d_in[8];
    float* out = (float*)d_out;

    const int N = in_sizes[0] / 128;
    const int E = in_sizes[7];

    // ws: KV (N*64 uint2) | Qp (N*64 u32) | rp (N+1)
    uint2*  KV = (uint2*)d_ws;
    uint32* Qp = (uint32*)(KV + (size_t)N * 64);
    int*    rp = (int*)(Qp + (size_t)N * 64);

    const int PB = (N + 127) / 128;              // proj blocks
    const int rp_blocks = (N + 1 + 255) / 256;   // row_ptr tail blocks

    proj_mfma_kernel<<<PB + rp_blocks, 256, 0, stream>>>(
        h, Wq, Wk, Wv, bq, bk, bv, Qp, KV, row, rp, N, E, PB);
    edge_attn_kernel<<<(N + 3) / 4, 128, 0, stream>>>(
        (const uint4*)Qp, (const uint4*)KV, rp, col, out, N);
}

// Round 11
// 89.993 us; speedup vs baseline: 1.0746x; 1.0746x over previous
//
#include <hip/hip_runtime.h>
#include <math.h>

typedef unsigned int uint32;
typedef _Float16 f16x8 __attribute__((ext_vector_type(8)));   // 8 f16 (4 VGPRs)
typedef _Float16 f16x2 __attribute__((ext_vector_type(2)));
typedef float f32x4 __attribute__((ext_vector_type(4)));      // MFMA accumulator

union frag_u { f16x8 h; uint32 u[4]; uint4 q; };

// ---------------------------------------------------------------------------
// SparseMHA, all-f16 intermediate, TWO launches (best measured config, R9):
//   proj: per-block LDS transpose of W (one mat at a time, 32KB, swizzled)
//         -> MFMA f16, wave owns 32 rows x 128 cols x 3 mats (A loaded once);
//         trailing blocks of the same grid compute row_ptr.
//   edge: lane=(edge-slot, head), fdot2 dots, 2-wave blocks, double-buffered.
// reshape(n,16,8) => flat idx = d*8+h, head = idx%8.
// Packed pair: u32 at [node*64+c] = (f16(x[c]), f16(x[c+64])).
//   Head h's dims = pair cols {h+8i, i=0..7}.
// KV rows interleaved as uint2; Q pre-scaled by 16^-0.5*log2(e) => p=exp2(q.k).
// ---------------------------------------------------------------------------

__device__ __forceinline__ uint32 pack_f16(float lo, float hi) {
    auto r = __builtin_amdgcn_cvt_pkrtz(lo, hi);   // one v_cvt_pkrtz_f16_f32
    return __builtin_bit_cast(uint32, r);
}
__device__ __forceinline__ float dot2acc(uint32 a, uint32 b, float c) {
#if __has_builtin(__builtin_amdgcn_fdot2)
    return __builtin_amdgcn_fdot2(__builtin_bit_cast(f16x2, a),
                                  __builtin_bit_cast(f16x2, b), c, false);
#else
    f16x2 av = __builtin_bit_cast(f16x2, a), bv = __builtin_bit_cast(f16x2, b);
    return fmaf((float)av[0], (float)bv[0], fmaf((float)av[1], (float)bv[1], c));
#endif
}

// ---- proj (blocks < PB): in-block W transpose + MFMA; else row_ptr --------
__global__ __launch_bounds__(256) void proj_mfma_kernel(
    const float* __restrict__ h,
    const float* __restrict__ Wq, const float* __restrict__ Wk,
    const float* __restrict__ Wv,
    const float* __restrict__ bq, const float* __restrict__ bk,
    const float* __restrict__ bv,
    uint32* __restrict__ Qp, uint2* __restrict__ KV,
    const int* __restrict__ row, int* __restrict__ rp,
    int N, int E, int PB)
{
    const int t = threadIdx.x;
    if ((int)blockIdx.x >= PB) {             // ---- row_ptr tail blocks ----
        int i = ((int)blockIdx.x - PB) * 256 + t;
        if (i > N) return;
        int lo = 0, hi = E;
        while (lo < hi) {
            int mid = (lo + hi) >> 1;
            if (row[mid] < i) lo = mid + 1; else hi = mid;
        }
        rp[i] = lo;
        return;
    }

    // LDS: one matrix of Wt, u32 kpairs [n][slot^swz][rem], 32 KB
    __shared__ uint32 Wl[8192];

    const int lane = t & 63;
    const int w = t >> 6;
    const int r = lane & 15, g = lane >> 4;
    const int rbase = blockIdx.x * 128 + w * 32;   // this wave's 32 rows

    // A fragments (f16), loaded exactly once per wave
    frag_u afr[2][4];                    // [ng][kb]
    const float4* h4 = reinterpret_cast<const float4*>(h);
    #pragma unroll
    for (int ng = 0; ng < 2; ++ng) {
        int arow = rbase + ng * 16 + r;
        bool av = arow < N;
        #pragma unroll
        for (int kb = 0; kb < 4; ++kb) {
            float4 x = make_float4(0.f,0.f,0.f,0.f), y = x;
            if (av) {
                size_t base = (size_t)arow * 32 + (kb * 4 + g) * 2;
                x = h4[base]; y = h4[base + 1];
            }
            afr[ng][kb].u[0] = pack_f16(x.x, x.y);
            afr[ng][kb].u[1] = pack_f16(x.z, x.w);
            afr[ng][kb].u[2] = pack_f16(y.x, y.y);
            afr[ng][kb].u[3] = pack_f16(y.z, y.w);
        }
    }

    const float SCALE_Q = 0.25f * 1.44269504f;   // 16^-0.5 * log2(e)
    uint32 kpk[4][2][4];                         // K results held for V pass

    #pragma unroll
    for (int mat = 0; mat < 3; ++mat) {
        const float* W = (mat == 0) ? Wq : (mat == 1) ? Wk : Wv;
        const float* bias = (mat == 0) ? bq : (mat == 1) ? bk : bv;

        // ---- transpose W (f32 [k][n]) -> Wl (f16 kpairs [n][kp], swizzled)
        __syncthreads();                         // previous mat's reads done
        {
            const float4* W4 = reinterpret_cast<const float4*>(W);
            #pragma unroll
            for (int i0 = 0; i0 < 8; ++i0) {
                int i = t + i0 * 256;            // i = k2*32 + nq
                int k2 = i >> 5, nq = i & 31;
                float4 a = W4[(k2 * 2) * 32 + nq];
                float4 b = W4[(k2 * 2 + 1) * 32 + nq];
                int slot = k2 >> 2, rem = k2 & 3;
                #pragma unroll
                for (int e = 0; e < 4; ++e) {
                    int n = nq * 4 + e;
                    float lo = (e == 0) ? a.x : (e == 1) ? a.y : (e == 2) ? a.z : a.w;
                    float hi = (e == 0) ? b.x : (e == 1) ? b.y : (e == 2) ? b.z : b.w;
                    Wl[n * 64 + ((slot ^ (n & 7)) << 2) + rem] = pack_f16(lo, hi);
                }
            }
        }
        __syncthreads();

        #pragma unroll
        for (int tp = 0; tp < 4; ++tp) {         // col-tile pair {tp, tp+4}
            const int c = tp * 16 + r;           // pair col (c, c+64)

            frag_u bfr[2][4];                    // [tti][kb]
            #pragma unroll
            for (int tti = 0; tti < 2; ++tti)
                #pragma unroll
                for (int kb = 0; kb < 4; ++kb) {
                    int n = (tp + 4 * tti) * 16 + r;
                    int s = kb * 4 + g;
                    bfr[tti][kb].q = *reinterpret_cast<const uint4*>(
                        &Wl[n * 64 + ((s ^ (n & 7)) << 2)]);
                }

            f32x4 acc[2][2];
            #pragma unroll
            for (int ng = 0; ng < 2; ++ng)
                #pragma unroll
                for (int tti = 0; tti < 2; ++tti)
                    acc[ng][tti] = (f32x4){0.f, 0.f, 0.f, 0.f};

            #pragma unroll
            for (int ng = 0; ng < 2; ++ng)
                #pragma unroll
                for (int tti = 0; tti < 2; ++tti)
                    #pragma unroll
                    for (int kb = 0; kb < 4; ++kb)
                        acc[ng][tti] = __builtin_amdgcn_mfma_f32_16x16x32_f16(
                            afr[ng][kb].h, bfr[tti][kb].h, acc[ng][tti], 0, 0, 0);

            // C/D map: col=lane&15, row=g*4+reg
            float blo = bias[c], bhi = bias[c + 64];
            #pragma unroll
            for (int ng = 0; ng < 2; ++ng) {
                #pragma unroll
                for (int reg = 0; reg < 4; ++reg) {
                    int node = rbase + ng * 16 + g * 4 + reg;
                    float lo = acc[ng][0][reg] + blo;
                    float hi = acc[ng][1][reg] + bhi;
                    if (mat == 0) {
                        if (node < N)
                            Qp[(size_t)node * 64 + c] = pack_f16(lo * SCALE_Q, hi * SCALE_Q);
                    } else if (mat == 1) {
                        kpk[tp][ng][reg] = pack_f16(lo, hi);
                    } else {
                        if (node < N)
                            KV[(size_t)node * 64 + c] =
                                make_uint2(kpk[tp][ng][reg], pack_f16(lo, hi));
                    }
                }
            }
        }
    }
}

// ---- fused edge stage: lane = (edge-slot, head); 2-wave blocks ------------
__global__ __launch_bounds__(128) void edge_attn_kernel(
    const uint32* __restrict__ Qp, const uint2* __restrict__ KV,
    const int* __restrict__ rp, const int* __restrict__ col,
    float* __restrict__ out, int N)
{
    const int lane = threadIdx.x & 63;
    const int node = blockIdx.x * 2 + (threadIdx.x >> 6);
    if (node >= N) return;
    const int hh   = lane & 7;      // head
    const int slot = lane >> 3;     // edge slot within group of 8

    const int start = rp[node], end = rp[node + 1];
    float* outp = out + (size_t)node * 128;
    if (start >= end) { outp[lane] = 0.f; outp[lane + 64] = 0.f; return; }
    const int last = end - 1;

    // Q for head hh: 8 packed f16 pairs (broadcast across slots)
    uint32 q[8];
    {
        const uint32* qrow = Qp + (size_t)node * 64;
        #pragma unroll
        for (int i = 0; i < 8; ++i) q[i] = qrow[hh + 8 * i];
    }

    float z = 0.f;
    float acc[16];
    #pragma unroll
    for (int i = 0; i < 16; ++i) acc[i] = 0.f;

    uint2 bufA[8], bufB[8];
    #define LOADG(buf, c0) { \
        const uint2* kvr = KV + (size_t)(c0) * 64; \
        _Pragma("unroll") \
        for (int i = 0; i < 8; ++i) (buf)[i] = kvr[hh + 8 * i]; }
    #define PROC(buf, gb) { \
        float s = 0.f; \
        _Pragma("unroll") \
        for (int i = 0; i < 8; ++i) s = dot2acc(q[i], (buf)[i].x, s); \
        float p = ((gb) + slot < end) ? __builtin_amdgcn_exp2f(s) : 0.f; \
        z += p; \
        _Pragma("unroll") \
        for (int i = 0; i < 8; ++i) { \
            f16x2 hv = __builtin_bit_cast(f16x2, (buf)[i].y); \
            acc[i]     = fmaf(p, (float)hv[0], acc[i]); \
            acc[8 + i] = fmaf(p, (float)hv[1], acc[8 + i]); } }

    int cA = col[min(start + slot, last)];
    int cB = col[min(start + 8 + slot, last)];
    LOADG(bufA, cA);
    int gb = start;
    while (true) {
        LOADG(bufB, cB);
        cA = col[min(gb + 16 + slot, last)];
        PROC(bufA, gb);
        gb += 8;
        if (gb >= end) break;
        LOADG(bufA, cA);
        cB = col[min(gb + 16 + slot, last)];
        PROC(bufB, gb);
        gb += 8;
        if (gb >= end) break;
    }

    // butterfly reduce across the 8 edge slots (xor lane bits 3..5)
    #pragma unroll
    for (int m = 8; m <= 32; m <<= 1) {
        z += __shfl_xor(z, m);
        #pragma unroll
        for (int i = 0; i < 16; ++i) acc[i] += __shfl_xor(acc[i], m);
    }

    // out flat idx = d*8 + h: lane writes d=slot and d=slot+8
    const float rz = 1.0f / z;
    outp[lane]      = acc[slot] * rz;
    outp[lane + 64] = acc[8 + slot] * rz;
}

extern "C" void kernel_launch(void* const* d_in, const int* in_sizes, int n_in,
                              void* d_out, int out_size, void* d_ws, size_t ws_size,
                              hipStream_t stream)
{
    const float* h  = (const float*)d_in[0];
    const float* Wq = (const float*)d_in[1];
    const float* bq = (const float*)d_in[2];
    const float* Wk = (const float*)d_in[3];
    const float* bk = (const float*)d_in[4];
    const float* Wv = (const float*)d_in[5];
    const float* bv = (const float*)d_in[6];
    const int* row  = (const int*)d_in[7];
    const int* col  = (const int*)d_in[8];
    float* out = (float*)d_out;

    const int N = in_sizes[0] / 128;
    const int E = in_sizes[7];

    // ws: KV (N*64 uint2) | Qp (N*64 u32) | rp (N+1)
    uint2*  KV = (uint2*)d_ws;
    uint32* Qp = (uint32*)(KV + (size_t)N * 64);
    int*    rp = (int*)(Qp + (size_t)N * 64);

    const int PB = (N + 127) / 128;              // proj blocks
    const int rp_blocks = (N + 1 + 255) / 256;   // row_ptr tail blocks

    proj_mfma_kernel<<<PB + rp_blocks, 256, 0, stream>>>(
        h, Wq, Wk, Wv, bq, bk, bv, Qp, KV, row, rp, N, E, PB);
    edge_attn_kernel<<<(N + 1) / 2, 128, 0, stream>>>(Qp, KV, rp, col, out, N);
}